// Round 6
// baseline (79.299 us; speedup 1.0000x reference)
//
#include <hip/hip_runtime.h>
#include <math.h>

#define NQ 10
#define NLAYERS 4
#define NGATES (NLAYERS * NQ)

typedef float v2f __attribute__((ext_vector_type(2)));
typedef float v4f __attribute__((ext_vector_type(4)));

__device__ __forceinline__ v2f mk2(float a, float b) { v2f r; r.x = a; r.y = b; return r; }

// packed gate entry m = {re, re, -im, im}; complex u*s / acc+u*s as v_pk_fma_f32
__device__ __forceinline__ v2f cmul_m(v4f m, v2f s) {
    v2f r = m.xy * s;
    return __builtin_elementwise_fma(m.zw, s.yx, r);
}
__device__ __forceinline__ v2f cfma_m(v2f acc, v4f m, v2f s) {
    acc = __builtin_elementwise_fma(m.xy, s, acc);
    acc = __builtin_elementwise_fma(m.zw, s.yx, acc);
    return acc;
}
// generic complex mul a*b ({re,im})
__device__ __forceinline__ v2f cmul(v2f a, v2f b) {
    v2f r = a.xx * b;
    return __builtin_elementwise_fma(mk2(-a.y, a.y), b.yx, r);
}
__device__ __forceinline__ v4f pack_u(float re, float im) {
    v4f m; m.x = re; m.y = re; m.z = -im; m.w = im; return m;
}

// CNOT-ring permutations (GF(2)-linear; closed forms verified R3/R4)
__host__ __device__ constexpr int pxor1(int v) {   // off = 1 (even layers)
    int y = v; y ^= y >> 1; y ^= y >> 2; y ^= y >> 4; y ^= y >> 8;
    return (y & 0x1FF) | (((y ^ (v >> 9)) & 1) << 9);
}
__host__ __device__ constexpr int pxor5(int v) {   // off = 5 (odd layers)
    int lo = v & 31, hi = (v >> 5) & 31;
    return (lo << 5) | (lo ^ hi);
}

// 1-qubit gate on register bit b (all indices constant after unroll)
__device__ __forceinline__ void apply_gate(v2f* st, const v4f* __restrict__ M, int b) {
    v4f m0 = M[0], m1 = M[1], m2 = M[2], m3 = M[3];
    #pragma unroll
    for (int g = 0; g < 16; ++g) {
        int r0 = ((g >> b) << (b + 1)) | (g & ((1 << b) - 1));
        int r1 = r0 | (1 << b);
        v2f s0v = st[r0], s1v = st[r1];
        v2f n0 = cmul_m(m0, s0v); n0 = cfma_m(n0, m1, s1v);
        v2f n1 = cmul_m(m2, s0v); n1 = cfma_m(n1, m3, s1v);
        st[r0] = n0; st[r1] = n1;
    }
}

// reload own row: lane L owns 32 consecutive v2f at element 33*L (b64, bank stride 2 = free)
__device__ __forceinline__ void load_row(v2f* st, const v2f* scratch, int lane) {
    const v2f* rp = scratch + 33 * lane;
    #pragma unroll
    for (int k = 0; k < 32; ++k) st[k] = rp[k];
}

// Layouts (2 samples/wave; s = lane>>5, sl = lane&31; amp idx bits [9:0], qubit q = bit 9-q):
//  A2: reg r = idx[4:0] (qubits 5..9), lane = idx[9:5]
//  B2: reg r = idx[9:5] (qubits 0..4), lane = idx[4:0]
//  LDS slot: 1056*s + 33*newlane + newreg  (stride 33: both scatter writes and row
//  reads have bank stride 2 -> 2-way aliasing = free per m136)
// Folds: layer-0 rotations -> encoding factors; layer-0 CNOT perm -> init index map
// (inverse pxor1: i_k=j_k^j_{k+1} k<=7, i_8=j_0^j_8^j_9, i_9=j_0^j_9);
// layer-3 CNOT perm -> measurement signs.
__global__ __launch_bounds__(64) void qsim_kernel(const float* __restrict__ x,
                                                  const float* __restrict__ w,
                                                  float* __restrict__ out)
{
    __shared__ __align__(16) v2f scratch[2112];
    __shared__ __align__(16) v4f matsL[NGATES * 4];
    __shared__ __align__(16) v2f encf[2][NQ][2];

    const int lane = threadIdx.x;
    const int s = lane >> 5, sl = lane & 31;
    const long sample = 2L * blockIdx.x + s;

    // ---- per-block setup: 40 variational mats (lanes 0..39) ----
    if (lane < NGATES) {
        float w0 = w[lane * 3 + 0], w1 = w[lane * 3 + 1], w2 = w[lane * 3 + 2];
        float hs = 0.5f * (w0 + w2), hd = 0.5f * (w0 - w2), hy = 0.5f * w1;
        float cy, sy, cs, ss, cd, sd;
        sincosf(hy, &sy, &cy);
        sincosf(hs, &ss, &cs);
        sincosf(hd, &sd, &cd);
        // U = RZ(w2) RY(w1) RZ(w0)
        matsL[lane * 4 + 0] = pack_u( cy * cs, -cy * ss);
        matsL[lane * 4 + 1] = pack_u(-sy * cd, -sy * sd);
        matsL[lane * 4 + 2] = pack_u( sy * cd, -sy * sd);
        matsL[lane * 4 + 3] = pack_u( cy * cs,  cy * ss);
    }
    __syncthreads();

    // ---- encoding factors with layer-0 rotations folded: g_q = U_{0,q} * f_q ----
    if (sl < NQ) {
        const float* xs = x + sample * (2 * NQ);
        float th = 0.7853981633974483f * (xs[sl] + 1.0f);
        float ph = 0.7853981633974483f * (xs[NQ + sl] + 1.0f);
        float cy, sy, cp, sp;
        sincosf(th, &sy, &cy);
        sincosf(ph, &sp, &cp);
        const float inv = 0.7071067811865476f;
        float a = (cy - sy) * inv, b = (cy + sy) * inv;
        v2f f0 = mk2(cp * a, -sp * a);   // column 0 of RZ(phi) RY(theta) H
        v2f f1 = mk2(cp * b,  sp * b);
        v4f M0 = matsL[sl * 4 + 0], M1 = matsL[sl * 4 + 1];
        v4f M2 = matsL[sl * 4 + 2], M3 = matsL[sl * 4 + 3];
        encf[s][sl][0] = cfma_m(cmul_m(M0, f0), M1, f1);
        encf[s][sl][1] = cfma_m(cmul_m(M2, f0), M3, f1);
    }
    __syncthreads();

    // ---- product-state init directly in A2-post-perm0 coordinates ----
    // j = (sl<<5)|r; pre-perm index i bits (selector for qubit q = i_{9-q}):
    //  q0: r0^sl4   q1: r0^sl3^sl4   q2: sl2^sl3   q3: sl1^sl2   q4: sl0^sl1
    //  q5: r4^sl0   q6: r3^r4        q7: r2^r3     q8: r1^r2     q9: r0^r1
    v2f st[32];
    {
        const int s0 = sl & 1, s1 = (sl >> 1) & 1, s2 = (sl >> 2) & 1,
                  s3 = (sl >> 3) & 1, s4 = (sl >> 4) & 1;
        v2f L = cmul(encf[s][2][s2 ^ s3], encf[s][3][s1 ^ s2]);
        L = cmul(L, encf[s][4][s0 ^ s1]);
        v2f A0 = cmul(encf[s][0][s4],     encf[s][1][s3 ^ s4]);
        v2f A1 = cmul(encf[s][0][1 ^ s4], encf[s][1][1 ^ s3 ^ s4]);
        v2f LA0 = cmul(L, A0), LA1 = cmul(L, A1);
        v2f G0 = encf[s][5][s0], G1 = encf[s][5][1 ^ s0];
        v2f D[2][2];
        D[0][0] = cmul(LA0, G0); D[0][1] = cmul(LA0, G1);
        D[1][0] = cmul(LA1, G0); D[1][1] = cmul(LA1, G1);
        v2f C98[2][2], C76[2][2];
        #pragma unroll
        for (int a2 = 0; a2 < 2; ++a2)
            #pragma unroll
            for (int b2 = 0; b2 < 2; ++b2) {
                C98[a2][b2] = cmul(encf[s][9][a2], encf[s][8][b2]);
                C76[a2][b2] = cmul(encf[s][7][a2], encf[s][6][b2]);
            }
        #pragma unroll
        for (int r = 0; r < 32; ++r) {
            const int r0 = r & 1, r1 = (r >> 1) & 1, r2 = (r >> 2) & 1,
                      r3 = (r >> 3) & 1, r4 = (r >> 4) & 1;
            st[r] = cmul(cmul(D[r0][r4], C98[r0 ^ r1][r1 ^ r2]), C76[r2 ^ r3][r3 ^ r4]);
        }
    }

    const int jb1 = pxor1(sl), jb5 = pxor5(sl);   // P(idx) = P(r<<5) ^ P(sl)

    // ---- layers 1..3 (layer 0 fully folded away) ----
    #pragma unroll
    for (int l = 1; l < NLAYERS; ++l) {
        // gates on qubits 5..9 in A2 (reg bit 9-q)
        #pragma unroll
        for (int q = 5; q <= 9; ++q)
            apply_gate(st, matsL + (l * NQ + q) * 4, 9 - q);

        // transpose A2 -> B2: value (sl,r) = amp (sl<<5)|r -> slot(lane'=r, reg'=sl)
        __syncthreads();
        {
            v2f* wp = scratch + 1056 * s + sl;
            #pragma unroll
            for (int r = 0; r < 32; ++r) wp[33 * r] = st[r];
        }
        __syncthreads();
        load_row(st, scratch, lane);

        // gates on qubits 0..4 in B2 (reg bit 4-q)
        #pragma unroll
        for (int q = 0; q <= 4; ++q)
            apply_gate(st, matsL + (l * NQ + q) * 4, 4 - q);

        if (l < NLAYERS - 1) {
            // perm-swap B2 -> A2 with this layer's CNOT ring folded into scatter
            __syncthreads();
            #pragma unroll
            for (int r = 0; r < 32; ++r) {
                const int jc = (l & 1) ? pxor5(r << 5) : pxor1(r << 5);  // compile-time
                const int j = jc ^ ((l & 1) ? jb5 : jb1);
                scratch[1056 * s + 33 * (j >> 5) + (j & 31)] = st[r];
            }
            __syncthreads();
            load_row(st, scratch, lane);
        }
    }

    // ---- measurement in B2 with layer-3 perm (pxor5) folded into signs ----
    // true final index j: j[9:5] = sl, j[4:0] = sl ^ r
    {
        float p[32];
        #pragma unroll
        for (int r = 0; r < 32; ++r) {
            v2f a = st[r];
            v2f sq = a * a;
            p[r] = sq.x + sq.y;
        }
        float t0 = 0.f, t1 = 0.f, t2 = 0.f, t3 = 0.f, t4 = 0.f;
        float s0a[16], s1a[8], s2a[4], s3a[2];
        #pragma unroll
        for (int k = 0; k < 16; ++k) { s0a[k] = p[2*k] + p[2*k+1]; t0 += p[2*k] - p[2*k+1]; }
        #pragma unroll
        for (int k = 0; k < 8; ++k)  { s1a[k] = s0a[2*k] + s0a[2*k+1]; t1 += s0a[2*k] - s0a[2*k+1]; }
        #pragma unroll
        for (int k = 0; k < 4; ++k)  { s2a[k] = s1a[2*k] + s1a[2*k+1]; t2 += s1a[2*k] - s1a[2*k+1]; }
        #pragma unroll
        for (int k = 0; k < 2; ++k)  { s3a[k] = s2a[2*k] + s2a[2*k+1]; t3 += s2a[2*k] - s2a[2*k+1]; }
        float S = s3a[0] + s3a[1];   t4 = s3a[0] - s3a[1];

        float acc[NQ];
        // q=0..4: j bit (9-q) = sl bit (4-q)
        #pragma unroll
        for (int q = 0; q < 5; ++q)
            acc[q] = ((sl >> (4 - q)) & 1) ? -S : S;
        // q=5..9: j bit k=9-q = sl_k ^ r_k  ->  lane-sign * reg-tree t_k
        acc[5] = ((sl >> 4) & 1) ? -t4 : t4;
        acc[6] = ((sl >> 3) & 1) ? -t3 : t3;
        acc[7] = ((sl >> 2) & 1) ? -t2 : t2;
        acc[8] = ((sl >> 1) & 1) ? -t1 : t1;
        acc[9] = (sl & 1)        ? -t0 : t0;

        // butterfly over the 5 lane bits (stays within each 32-lane half)
        #pragma unroll
        for (int q = 0; q < NQ; ++q) {
            #pragma unroll
            for (int o = 16; o >= 1; o >>= 1)
                acc[q] += __shfl_xor(acc[q], o);
        }
        float v = acc[0];
        #pragma unroll
        for (int q = 1; q < NQ; ++q) v = (sl == q) ? acc[q] : v;
        if (sl < NQ)
            out[sample * NQ + sl] = v;
    }
}

extern "C" void kernel_launch(void* const* d_in, const int* in_sizes, int n_in,
                              void* d_out, int out_size, void* d_ws, size_t ws_size,
                              hipStream_t stream) {
    const float* x = (const float*)d_in[0];   // (16,256,20) fp32
    const float* w = (const float*)d_in[1];   // (4,10,3)   fp32
    float* out = (float*)d_out;               // (16,256,10) fp32
    const int n_samples = in_sizes[0] / (2 * NQ);  // 4096
    qsim_kernel<<<n_samples / 2, 64, 0, stream>>>(x, w, out);
}